// Round 1
// baseline (237.978 us; speedup 1.0000x reference)
//
#include <hip/hip_runtime.h>

// HollywoodFFT: B=4096 rows of N=4096 complex FFT (split re/im fp32).
// Radix-16 x 3 passes, one workgroup (256 thr) per row, single 35KB LDS
// buffer, skewed layouts for <=2-way bank aliasing (free per m136).
// n = a + 16b + 256c ; k = u + 16v + 256w (digits in [0,16)):
//   S1[a][b][u] = DFT16_c x[a+16b+256c]
//   S2 = S1 * W256^{b u}
//   S3[a][u][v] = DFT16_b S2
//   S4 = S3 * W4096^{a(u+16v)}
//   X[u+16v+256w] = DFT16_a S4

#define NFFT 4096

__device__ __forceinline__ void fft16(float xr[16], float xi[16]) {
    // natural-order in/out 16-point DFT: bit-rev permute + 4 radix-2 DIT stages
    const int br[16] = {0,8,4,12,2,10,6,14,1,9,5,13,3,11,7,15};
    float yr[16], yi[16];
#pragma unroll
    for (int j = 0; j < 16; ++j) { yr[j] = xr[br[j]]; yi[j] = xi[br[j]]; }
    // W16^j = exp(-2*pi*i*j/16), j = 0..7
    const float W16r[8] = { 1.0f,  0.92387953251128675613f,  0.70710678118654752440f,
                            0.38268343236508977173f,  0.0f, -0.38268343236508977173f,
                           -0.70710678118654752440f, -0.92387953251128675613f };
    const float W16i[8] = { 0.0f, -0.38268343236508977173f, -0.70710678118654752440f,
                           -0.92387953251128675613f, -1.0f, -0.92387953251128675613f,
                           -0.70710678118654752440f, -0.38268343236508977173f };
#pragma unroll
    for (int s = 0; s < 4; ++s) {
        const int stride = 1 << s;
        const int tm = 8 >> s;
#pragma unroll
        for (int g = 0; g < 16; g += 2 * stride) {
#pragma unroll
            for (int p = 0; p < stride; ++p) {
                const int i0 = g + p, i1 = i0 + stride;
                const float twr = W16r[p * tm], twi = W16i[p * tm];
                const float brr = yr[i1] * twr - yi[i1] * twi;
                const float bii = yr[i1] * twi + yi[i1] * twr;
                const float ar = yr[i0], ai = yi[i0];
                yr[i0] = ar + brr; yi[i0] = ai + bii;
                yr[i1] = ar - brr; yi[i1] = ai - bii;
            }
        }
    }
#pragma unroll
    for (int j = 0; j < 16; ++j) { xr[j] = yr[j]; xi[j] = yi[j]; }
}

__global__ __launch_bounds__(256, 4)
void HollywoodFFT_53584011985637_kernel(const float* __restrict__ xre,
                                        const float* __restrict__ xim,
                                        float* __restrict__ outre,
                                        float* __restrict__ outim) {
    // idx1(a,b,u) = a + 16b + 264u  (max 4215)  -- A-write / B-read, 2-way max
    // idx2(a,u,v) = 2a + 17u + 272v (max 4365)  -- B-write / C-read, 2-way max
    __shared__ float lr[4368];
    __shared__ float li[4368];

    const int t = threadIdx.x;
    const long long row = blockIdx.x;
    const float* __restrict__ xr_row = xre + row * NFFT;
    const float* __restrict__ xi_row = xim + row * NFFT;

    float vr[16], vi[16];
    const int a = t & 15;          // pass A/B 'a' digit
    // ---- Pass A: thread (a, b=t>>4), DFT16 over c. n = t + 256c (coalesced) ----
#pragma unroll
    for (int c = 0; c < 16; ++c) {
        vr[c] = xr_row[t + 256 * c];
        vi[c] = xi_row[t + 256 * c];
    }
    fft16(vr, vi);
#pragma unroll
    for (int u = 0; u < 16; ++u) {     // addr = t + 264u (lane-consecutive)
        lr[t + 264 * u] = vr[u];
        li[t + 264 * u] = vi[u];
    }
    __syncthreads();

    // ---- Pass B: thread (a, u=t>>4). Read over b, twiddle W256^{bu}, DFT16 over b ----
    const int u = t >> 4;
    {
        float s0, c0;
        __sincosf(-6.28318530717958647692f * (float)u * (1.0f / 256.0f), &s0, &c0);
        float twr = 1.0f, twi = 0.0f;  // W256^{b*u} via recurrence
#pragma unroll
        for (int bb = 0; bb < 16; ++bb) {
            const int id = a + 16 * bb + 264 * u;
            const float rr = lr[id], ii = li[id];
            vr[bb] = rr * twr - ii * twi;
            vi[bb] = rr * twi + ii * twr;
            const float ntr = twr * c0 - twi * s0;
            twi = twr * s0 + twi * c0;
            twr = ntr;
        }
    }
    __syncthreads();                   // all idx1 reads done before idx2 writes
    fft16(vr, vi);
#pragma unroll
    for (int v = 0; v < 16; ++v) {
        lr[2 * a + 17 * u + 272 * v] = vr[v];
        li[2 * a + 17 * u + 272 * v] = vi[v];
    }
    __syncthreads();

    // ---- Pass C: thread (u2=t&15, v2=t>>4). Read over a, twiddle W4096^{a(u2+16v2)},
    //      DFT16 over a, store X[t + 256w] (coalesced) ----
    const int u2 = t & 15, v2 = t >> 4;
    {
        float s0, c0;
        __sincosf(-6.28318530717958647692f * (float)(u2 + 16 * v2) * (1.0f / 4096.0f),
                  &s0, &c0);
        float twr = 1.0f, twi = 0.0f;  // W4096^{a*(u2+16v2)} via recurrence
#pragma unroll
        for (int aa = 0; aa < 16; ++aa) {
            const int id = 2 * aa + 17 * u2 + 272 * v2;
            const float rr = lr[id], ii = li[id];
            vr[aa] = rr * twr - ii * twi;
            vi[aa] = rr * twi + ii * twr;
            const float ntr = twr * c0 - twi * s0;
            twi = twr * s0 + twi * c0;
            twr = ntr;
        }
    }
    fft16(vr, vi);

    float* __restrict__ or_row = outre + row * NFFT;
    float* __restrict__ oi_row = outim + row * NFFT;
#pragma unroll
    for (int w = 0; w < 16; ++w) {
        or_row[t + 256 * w] = vr[w];
        oi_row[t + 256 * w] = vi[w];
    }
}

extern "C" void kernel_launch(void* const* d_in, const int* in_sizes, int n_in,
                              void* d_out, int out_size, void* d_ws, size_t ws_size,
                              hipStream_t stream) {
    const float* xre = (const float*)d_in[0];
    const float* xim = (const float*)d_in[1];
    const int B = in_sizes[0] / NFFT;            // 4096 rows
    float* out = (float*)d_out;
    float* outre = out;
    float* outim = out + (size_t)B * NFFT;       // outputs concatenated flat
    HollywoodFFT_53584011985637_kernel<<<dim3(B), dim3(256), 0, stream>>>(
        xre, xim, outre, outim);
}

// Round 2
// 235.361 us; speedup vs baseline: 1.0111x; 1.0111x over previous
//
#include <hip/hip_runtime.h>

// HollywoodFFT: B=4096 rows of N=4096 complex FFT (split re/im fp32).
// Radix-16 x 3 passes, one workgroup (256 thr) per row.
// R2 changes: 16B/lane global I/O via LDS staging rounds; zero-padding
// XOR-swizzled LDS layouts (exactly 32 KB -> 5 blocks/CU); NT stores.
// n = a + 16b + 256c ; k = u + 16v + 256w (digits in [0,16)):
//   S1[a][b][u] = DFT16_c x[a+16b+256c]
//   S2 = S1 * W256^{b u}
//   S3[a][u][v] = DFT16_b S2
//   S4 = S3 * W4096^{a(u+16v)}
//   X[u+16v+256w] = DFT16_a S4
// LDS layouts (word addr in [0,4096), all accesses <=2-way bank-aliased):
//   L0 (stage-in):  n                      (natural)
//   L1: addr(a,b,u) = a + 16*(b^u) + 256*u
//   L2: addr(a,u,v) = (a^u) + 16*(u^v) + 256*v
//   L3 (stage-out): k                      (natural)

#define NFFT 4096

typedef float fvec4 __attribute__((ext_vector_type(4)));

__device__ __forceinline__ void fft16(float xr[16], float xi[16]) {
    // natural-order in/out 16-point DFT: bit-rev permute + 4 radix-2 DIT stages
    const int br[16] = {0,8,4,12,2,10,6,14,1,9,5,13,3,11,7,15};
    float yr[16], yi[16];
#pragma unroll
    for (int j = 0; j < 16; ++j) { yr[j] = xr[br[j]]; yi[j] = xi[br[j]]; }
    const float W16r[8] = { 1.0f,  0.92387953251128675613f,  0.70710678118654752440f,
                            0.38268343236508977173f,  0.0f, -0.38268343236508977173f,
                           -0.70710678118654752440f, -0.92387953251128675613f };
    const float W16i[8] = { 0.0f, -0.38268343236508977173f, -0.70710678118654752440f,
                           -0.92387953251128675613f, -1.0f, -0.92387953251128675613f,
                           -0.70710678118654752440f, -0.38268343236508977173f };
#pragma unroll
    for (int s = 0; s < 4; ++s) {
        const int stride = 1 << s;
        const int tm = 8 >> s;
#pragma unroll
        for (int g = 0; g < 16; g += 2 * stride) {
#pragma unroll
            for (int p = 0; p < stride; ++p) {
                const int i0 = g + p, i1 = i0 + stride;
                const float twr = W16r[p * tm], twi = W16i[p * tm];
                const float brr = yr[i1] * twr - yi[i1] * twi;
                const float bii = yr[i1] * twi + yi[i1] * twr;
                const float ar = yr[i0], ai = yi[i0];
                yr[i0] = ar + brr; yi[i0] = ai + bii;
                yr[i1] = ar - brr; yi[i1] = ai - bii;
            }
        }
    }
#pragma unroll
    for (int j = 0; j < 16; ++j) { xr[j] = yr[j]; xi[j] = yi[j]; }
}

__global__ __launch_bounds__(256, 5)
void HollywoodFFT_53584011985637_kernel(const float* __restrict__ xre,
                                        const float* __restrict__ xim,
                                        float* __restrict__ outre,
                                        float* __restrict__ outim) {
    __shared__ __align__(16) float lr[NFFT];
    __shared__ __align__(16) float li[NFFT];

    const int t = threadIdx.x;
    const long long row = blockIdx.x;
    const float* __restrict__ xr_row = xre + row * NFFT;
    const float* __restrict__ xi_row = xim + row * NFFT;

    // ---- Stage-in: 16B/lane vector loads -> LDS natural layout ----
    {
        const fvec4* __restrict__ xr4 = (const fvec4*)xr_row;
        const fvec4* __restrict__ xi4 = (const fvec4*)xi_row;
        fvec4 rr[4], ii[4];
#pragma unroll
        for (int q = 0; q < 4; ++q) { rr[q] = xr4[t + 256 * q]; ii[q] = xi4[t + 256 * q]; }
#pragma unroll
        for (int q = 0; q < 4; ++q) {
            ((fvec4*)lr)[t + 256 * q] = rr[q];
            ((fvec4*)li)[t + 256 * q] = ii[q];
        }
    }
    __syncthreads();

    float vr[16], vi[16];
    const int a = t & 15;
    const int u = t >> 4;

    // ---- Pass A: thread (a, b=t>>4), DFT16 over c. read n = t + 256c ----
#pragma unroll
    for (int c = 0; c < 16; ++c) { vr[c] = lr[t + 256 * c]; vi[c] = li[t + 256 * c]; }
    fft16(vr, vi);
    __syncthreads();                 // all L0 reads done before L1 writes
#pragma unroll
    for (int uu = 0; uu < 16; ++uu) {     // L1: a + 16*(b^u) + 256*u ; here b = t>>4
        const int id = a + 16 * ((t >> 4) ^ uu) + 256 * uu;
        lr[id] = vr[uu]; li[id] = vi[uu];
    }
    __syncthreads();

    // ---- Pass B: thread (a, u). Read over b w/ twiddle W256^{bu}, DFT16 over b ----
    {
        float s0, c0;
        __sincosf(-6.28318530717958647692f * (float)u * (1.0f / 256.0f), &s0, &c0);
        float twr = 1.0f, twi = 0.0f;
#pragma unroll
        for (int bb = 0; bb < 16; ++bb) {
            const int id = a + 16 * (bb ^ u) + 256 * u;
            const float rr = lr[id], ii = li[id];
            vr[bb] = rr * twr - ii * twi;
            vi[bb] = rr * twi + ii * twr;
            const float ntr = twr * c0 - twi * s0;
            twi = twr * s0 + twi * c0;
            twr = ntr;
        }
    }
    fft16(vr, vi);
    __syncthreads();                 // all L1 reads done before L2 writes
#pragma unroll
    for (int v = 0; v < 16; ++v) {   // L2: (a^u) + 16*(u^v) + 256*v
        const int id = (a ^ u) + 16 * (u ^ v) + 256 * v;
        lr[id] = vr[v]; li[id] = vi[v];
    }
    __syncthreads();

    // ---- Pass C: thread (u2=t&15, v2=t>>4). Read over a w/ twiddle, DFT16 over a ----
    const int u2 = t & 15, v2 = t >> 4;
    {
        float s0, c0;
        __sincosf(-6.28318530717958647692f * (float)(u2 + 16 * v2) * (1.0f / 4096.0f),
                  &s0, &c0);
        float twr = 1.0f, twi = 0.0f;
#pragma unroll
        for (int aa = 0; aa < 16; ++aa) {
            const int id = (aa ^ u2) + 16 * (u2 ^ v2) + 256 * v2;
            const float rr = lr[id], ii = li[id];
            vr[aa] = rr * twr - ii * twi;
            vi[aa] = rr * twi + ii * twr;
            const float ntr = twr * c0 - twi * s0;
            twi = twr * s0 + twi * c0;
            twr = ntr;
        }
    }
    fft16(vr, vi);
    __syncthreads();                 // all L2 reads done before L3 writes
#pragma unroll
    for (int w = 0; w < 16; ++w) {   // L3: k = u2 + 16*v2 + 256*w (natural)
        const int id = u2 + 16 * v2 + 256 * w;
        lr[id] = vr[w]; li[id] = vi[w];
    }
    __syncthreads();

    // ---- Stage-out: LDS natural -> 16B/lane NT vector stores ----
    {
        float* __restrict__ or_row = outre + row * NFFT;
        float* __restrict__ oi_row = outim + row * NFFT;
#pragma unroll
        for (int q = 0; q < 4; ++q) {
            fvec4 rr = ((const fvec4*)lr)[t + 256 * q];
            fvec4 ii = ((const fvec4*)li)[t + 256 * q];
            __builtin_nontemporal_store(rr, (fvec4*)or_row + t + 256 * q);
            __builtin_nontemporal_store(ii, (fvec4*)oi_row + t + 256 * q);
        }
    }
}

extern "C" void kernel_launch(void* const* d_in, const int* in_sizes, int n_in,
                              void* d_out, int out_size, void* d_ws, size_t ws_size,
                              hipStream_t stream) {
    const float* xre = (const float*)d_in[0];
    const float* xim = (const float*)d_in[1];
    const int B = in_sizes[0] / NFFT;            // 4096 rows
    float* out = (float*)d_out;
    float* outre = out;
    float* outim = out + (size_t)B * NFFT;       // outputs concatenated flat
    HollywoodFFT_53584011985637_kernel<<<dim3(B), dim3(256), 0, stream>>>(
        xre, xim, outre, outim);
}